// Round 6
// baseline (62.526 us; speedup 1.0000x reference)
//
#include <hip/hip_runtime.h>
#include <hip/hip_bf16.h>

// KANLinear as bf16 MFMA GEMM, K = i*8 + c (c: spline q=2..7 pre-scaled 1/6,
// silu, pad). Round 6: NO LDS, NO barriers. A-fragments computed in registers
// (one phi_pack per lane per (m,ks)); B-fragments loaded straight from a
// repacked 1MB image in ws, laid out so each fragment is one coalesced
// dwordx4 load (frag base + lane*16). BN=256 single column block kills the
// by-duplication of phi. Wave tile 32x128 (acc[2][8]); 4 waves/block,
// 256 blocks = 1/CU. Pure streaming pipeline: bB/bA/x prefetched one
// phase/iter ahead in registers.

#define M_TOTAL 16384
#define IF 256
#define OF 256
#define NKT 32
#define THREADS 256   // 4 waves: wr = row group (32 rows), wn = col group (128)

typedef __attribute__((ext_vector_type(8))) __bf16 bf16x8;
typedef __attribute__((ext_vector_type(4))) float f32x4;

// Image: bf16x8 unit index = frag*64 + lane, frag = ((kt*2 + wn)*2 + ks)*8 + n.
// Fragment (kt,wn,ks,n), lane: col = wn*128 + n*16 + (lane&15),
// i = kt*8 + ks*4 + (lane>>4), slots c=0..7.
__global__ void repack_w(const float* __restrict__ w, __bf16* __restrict__ img) {
    int g = blockIdx.x * 256 + threadIdx.x;      // 0..65535
    int lane = g & 63, frag = g >> 6;
    int n  = frag & 7;
    int ks = (frag >> 3) & 1;
    int wn = (frag >> 4) & 1;
    int kt = frag >> 5;
    int col = wn * 128 + n * 16 + (lane & 15);
    int i   = kt * 8 + ks * 4 + (lane >> 4);
    const float s6 = 1.0f / 6.0f;
    bf16x8 v;
#pragma unroll
    for (int c = 0; c < 8; ++c) {
        float f = (c < 6) ? w[(size_t)i * 2304 + col * 9 + c + 2] * s6
                : (c == 6) ? w[(size_t)i * 2304 + col * 9 + 8] : 0.0f;
        v[c] = (__bf16)f;
    }
    ((bf16x8*)img)[g] = v;
}

// one x -> A-fragment {shift-selected cubic B-spline pieces, silu, 0}
__device__ __forceinline__ bf16x8 phi_pack(float x) {
    float t  = fmaf(x, 2.5f, 5.5f);
    float fi = floorf(t);                // 5,6,7 for x in [0,1)
    float u  = (t - fi) - 3.0f;          // [-3,-2)
    float u2 = u * u, u3 = u2 * u;
    float w0 = fmaf(-1.f, u3, fmaf( 3.f, u2, fmaf(-3.f, u, 1.f)));
    float w1 = fmaf( 3.f, u3, fmaf(-6.f, u2, 4.f));
    float w2 = fmaf(-3.f, u3, fmaf( 3.f, u2, fmaf( 3.f, u, 1.f)));
    float w3 = u3;
    bool e1 = fi > 5.5f;                 // idx >= 6
    bool e2 = fi > 6.5f;                 // idx == 7
    float v0 = e1 ? 0.f : w0;
    float v1 = e2 ? 0.f : (e1 ? w0 : w1);
    float v2 = e2 ? w0  : (e1 ? w1 : w2);
    float v3 = e2 ? w1  : (e1 ? w2 : w3);
    float v4 = e2 ? w2  : (e1 ? w3 : 0.f);
    float v5 = e2 ? w3  : 0.f;
    float sl = x * __builtin_amdgcn_rcpf(1.f + __expf(-x));
    bf16x8 v;
    v[0] = (__bf16)v0; v[1] = (__bf16)v1; v[2] = (__bf16)v2; v[3] = (__bf16)v3;
    v[4] = (__bf16)v4; v[5] = (__bf16)v5; v[6] = (__bf16)sl; v[7] = (__bf16)0.f;
    return v;
}

// Slow-path gather of one B fragment directly from W (used only if ws absent).
__device__ __forceinline__ bf16x8 gather_frag(const float* __restrict__ W,
                                              int kt, int wn, int ks, int n, int lane) {
    int col = wn * 128 + n * 16 + (lane & 15);
    int i   = kt * 8 + ks * 4 + (lane >> 4);
    const float s6 = 1.0f / 6.0f;
    bf16x8 v;
#pragma unroll
    for (int c = 0; c < 8; ++c) {
        float f = (c < 6) ? W[(size_t)i * 2304 + col * 9 + c + 2] * s6
                : (c == 6) ? W[(size_t)i * 2304 + col * 9 + 8] : 0.0f;
        v[c] = (__bf16)f;
    }
    return v;
}

template <bool DIRECT_B>
__global__ __launch_bounds__(THREADS, 1)
void kan_gemm(const float* __restrict__ X, const __bf16* __restrict__ Bimg,
              const float* __restrict__ W, float* __restrict__ Y) {
    const int tid  = threadIdx.x;
    const int lane = tid & 63;
    const int wv   = tid >> 6;       // 0..3
    const int wr   = wv >> 1;        // row group 0..1 (32 rows)
    const int wn   = wv & 1;         // col group 0..1 (128 cols)
    const int l15  = lane & 15;
    const int l4   = lane >> 4;
    const int brow0 = blockIdx.x * 64;

    // x: row = brow0 + wr*32 + m*16 + l15 ; col = kt*8 + ks*4 + l4
    const float* x0 = X + (size_t)(brow0 + wr * 32 + l15) * IF + l4;

    // B image base for this wave's column group (bf16x8 units)
    const bf16x8* iv = (const bf16x8*)Bimg + (size_t)wn * 1024 + lane;
    // + kt*2048 + ks*512 + n*64

    f32x4 acc[2][8] = {};
    bf16x8 bA[8], bB[8];
    bf16x8 aC[2][2], aN[2][2];
    float  xn[2][2];

    // ---- prologue: x(0) -> aC ; bA <- frag(kt=0, ks=0) ----
#pragma unroll
    for (int m = 0; m < 2; ++m)
#pragma unroll
        for (int ks = 0; ks < 2; ++ks)
            aC[m][ks] = phi_pack(x0[m * 4096 + ks * 4]);

    if (!DIRECT_B) {
#pragma unroll
        for (int n = 0; n < 8; ++n) bA[n] = iv[n * 64];
    } else {
#pragma unroll
        for (int n = 0; n < 8; ++n) bA[n] = gather_frag(W, 0, wn, 0, n, lane);
    }

    for (int kt = 0; kt < NKT; ++kt) {
        const int ktn = (kt < NKT - 1) ? kt + 1 : kt;   // clamped prefetch

        // ---- x prefetch for kt+1 ----
#pragma unroll
        for (int m = 0; m < 2; ++m)
#pragma unroll
            for (int ks = 0; ks < 2; ++ks)
                xn[m][ks] = x0[m * 4096 + ktn * 8 + ks * 4];

        // ---- bB <- frag(kt, ks=1) ----
        if (!DIRECT_B) {
            const bf16x8* p = iv + kt * 2048 + 512;
#pragma unroll
            for (int n = 0; n < 8; ++n) bB[n] = p[n * 64];
        } else {
#pragma unroll
            for (int n = 0; n < 8; ++n) bB[n] = gather_frag(W, kt, wn, 1, n, lane);
        }

        // ---- phase 0: MFMA with bA (ks=0) ----
#pragma unroll
        for (int n = 0; n < 8; ++n)
#pragma unroll
            for (int m = 0; m < 2; ++m)
                acc[m][n] = __builtin_amdgcn_mfma_f32_16x16x32_bf16(aC[m][0], bA[n], acc[m][n], 0, 0, 0);

        // ---- phi for kt+1 (covers bB latency) ----
#pragma unroll
        for (int m = 0; m < 2; ++m)
#pragma unroll
            for (int ks = 0; ks < 2; ++ks)
                aN[m][ks] = phi_pack(xn[m][ks]);

        // ---- bA <- frag(kt+1, ks=0) ----
        if (!DIRECT_B) {
            const bf16x8* p = iv + ktn * 2048;
#pragma unroll
            for (int n = 0; n < 8; ++n) bA[n] = p[n * 64];
        } else {
#pragma unroll
            for (int n = 0; n < 8; ++n) bA[n] = gather_frag(W, ktn, wn, 0, n, lane);
        }

        // ---- phase 1: MFMA with bB (ks=1) ----
#pragma unroll
        for (int n = 0; n < 8; ++n)
#pragma unroll
            for (int m = 0; m < 2; ++m)
                acc[m][n] = __builtin_amdgcn_mfma_f32_16x16x32_bf16(aC[m][1], bB[n], acc[m][n], 0, 0, 0);

        // ---- commit next A ----
#pragma unroll
        for (int m = 0; m < 2; ++m)
#pragma unroll
            for (int ks = 0; ks < 2; ++ks)
                aC[m][ks] = aN[m][ks];
    }

    // ---- epilogue: C/D layout col=lane&15, row=(lane>>4)*4+r ----
#pragma unroll
    for (int m = 0; m < 2; ++m)
#pragma unroll
        for (int n = 0; n < 8; ++n) {
            int col  = wn * 128 + n * 16 + l15;
            int row0 = brow0 + wr * 32 + m * 16 + l4 * 4;
#pragma unroll
            for (int r = 0; r < 4; ++r)
                Y[(size_t)(row0 + r) * OF + col] = acc[m][n][r];
        }
}

extern "C" void kernel_launch(void* const* d_in, const int* in_sizes, int n_in,
                              void* d_out, int out_size, void* d_ws, size_t ws_size,
                              hipStream_t stream) {
    const float* X = (const float*)d_in[0];
    const float* W = (const float*)d_in[1];
    float* Y = (float*)d_out;

    size_t need = (size_t)65536 * 16;                   // 1.0 MB image
    dim3 grid(M_TOTAL / 64);                            // 256 blocks

    if (d_ws != nullptr && ws_size >= need) {
        __bf16* img = (__bf16*)d_ws;
        repack_w<<<dim3(256), dim3(256), 0, stream>>>(W, img);
        kan_gemm<false><<<grid, dim3(THREADS), 0, stream>>>(X, img, W, Y);
    } else {
        kan_gemm<true><<<grid, dim3(THREADS), 0, stream>>>(X, nullptr, W, Y);
    }
}

// Round 7
// 38.601 us; speedup vs baseline: 1.6198x; 1.6198x over previous
//
#include <hip/hip_runtime.h>
#include <hip/hip_bf16.h>

// KANLinear as bf16 MFMA GEMM, K = i*8 + c (c: spline q=2..7 pre-scaled 1/6,
// silu, pad). Round 7 split design:
//  - A (phi) computed EXACTLY ONCE chip-wide: one phi_pack per thread per kt,
//    shared across the block through a double-buffered 8KB LDS tile
//    (XOR-swizzled, conflict-free write & read). Barrier only orders ds_writes
//    (no global-latency drain behind it).
//  - B read straight into registers from a repacked 1MB image (L2-resident),
//    wave tile 64x32 => every B fragment fetched exactly once per block.
//  - 512 thr / 8 waves per block, grid 256 = 1 block/CU, 2 waves/SIMD.

#define M_TOTAL 16384
#define IF 256
#define OF 256
#define NKT 32
#define THREADS 512

typedef __attribute__((ext_vector_type(8))) __bf16 bf16x8;
typedef __attribute__((ext_vector_type(4))) float f32x4;

// Image: 16B unit index = frag*64 + lane; frag = kt*32 + ks*16 + wn*2 + n.
// Fragment (kt,ks,wn,n), lane: col = wn*32 + n*16 + (lane&15),
// i = kt*8 + ks*4 + (lane>>4), 8 c-slots per unit.
__global__ void repack_w(const float* __restrict__ w, __bf16* __restrict__ img) {
    int g = blockIdx.x * 256 + threadIdx.x;      // 0..65535
    int lane = g & 63, frag = g >> 6;
    int n  = frag & 1;
    int wn = (frag >> 1) & 7;
    int ks = (frag >> 4) & 1;
    int kt = frag >> 5;
    int col = wn * 32 + n * 16 + (lane & 15);
    int i   = kt * 8 + ks * 4 + (lane >> 4);
    const float s6 = 1.0f / 6.0f;
    bf16x8 v;
#pragma unroll
    for (int c = 0; c < 8; ++c) {
        float f = (c < 6) ? w[(size_t)i * 2304 + col * 9 + c + 2] * s6
                : (c == 6) ? w[(size_t)i * 2304 + col * 9 + 8] : 0.0f;
        v[c] = (__bf16)f;
    }
    ((bf16x8*)img)[g] = v;
}

// one x -> A-fragment {shift-selected cubic B-spline pieces, silu, 0}
__device__ __forceinline__ bf16x8 phi_pack(float x) {
    float t  = fmaf(x, 2.5f, 5.5f);
    float fi = floorf(t);                // 5,6,7 for x in [0,1)
    float u  = (t - fi) - 3.0f;          // [-3,-2)
    float u2 = u * u, u3 = u2 * u;
    float w0 = fmaf(-1.f, u3, fmaf( 3.f, u2, fmaf(-3.f, u, 1.f)));
    float w1 = fmaf( 3.f, u3, fmaf(-6.f, u2, 4.f));
    float w2 = fmaf(-3.f, u3, fmaf( 3.f, u2, fmaf( 3.f, u, 1.f)));
    float w3 = u3;
    bool e1 = fi > 5.5f;                 // idx >= 6
    bool e2 = fi > 6.5f;                 // idx == 7
    float v0 = e1 ? 0.f : w0;
    float v1 = e2 ? 0.f : (e1 ? w0 : w1);
    float v2 = e2 ? w0  : (e1 ? w1 : w2);
    float v3 = e2 ? w1  : (e1 ? w2 : w3);
    float v4 = e2 ? w2  : (e1 ? w3 : 0.f);
    float v5 = e2 ? w3  : 0.f;
    float sl = x * __builtin_amdgcn_rcpf(1.f + __expf(-x));
    bf16x8 v;
    v[0] = (__bf16)v0; v[1] = (__bf16)v1; v[2] = (__bf16)v2; v[3] = (__bf16)v3;
    v[4] = (__bf16)v4; v[5] = (__bf16)v5; v[6] = (__bf16)sl; v[7] = (__bf16)0.f;
    return v;
}

// Slow-path gather of one B fragment directly from W (used only if ws absent).
__device__ __forceinline__ bf16x8 gather_frag(const float* __restrict__ W,
                                              int kt, int wn, int ks, int n, int lane) {
    int col = wn * 32 + n * 16 + (lane & 15);
    int i   = kt * 8 + ks * 4 + (lane >> 4);
    const float s6 = 1.0f / 6.0f;
    bf16x8 v;
#pragma unroll
    for (int c = 0; c < 8; ++c) {
        float f = (c < 6) ? W[(size_t)i * 2304 + col * 9 + c + 2] * s6
                : (c == 6) ? W[(size_t)i * 2304 + col * 9 + 8] : 0.0f;
        v[c] = (__bf16)f;
    }
    return v;
}

// One K-step: read A frags from LDS[kt&1], prefetch B(kt+1)->BN, MFMA with BC,
// phi(x[kt+1]) -> LDS[(kt+1)&1], barrier.
#define KT_BODY(KT, BC, BN)                                                   \
    {                                                                         \
        const int kt_ = (KT);                                                 \
        const bool more_ = (kt_ + 1 < NKT);                                   \
        const char* Ar_ = lds + ((kt_ & 1) << 13);                            \
        char* Aw_ = lds + (((kt_ + 1) & 1) << 13);                            \
        int xoff_ = (more_ ? (kt_ + 1) : kt_) * 8;                            \
        float xn_ = xsrc[xoff_];                                              \
        if (more_) {                                                          \
            if (!DIRECT_B) {                                                  \
                const char* p_ = ib + (size_t)(kt_ + 1) * 32768;              \
                BN[0] = *(const bf16x8*)(p_);                                 \
                BN[1] = *(const bf16x8*)(p_ + 1024);                          \
                BN[2] = *(const bf16x8*)(p_ + 16384);                         \
                BN[3] = *(const bf16x8*)(p_ + 17408);                         \
            } else {                                                          \
                BN[0] = gather_frag(W, kt_ + 1, wn, 0, 0, lane);              \
                BN[1] = gather_frag(W, kt_ + 1, wn, 0, 1, lane);              \
                BN[2] = gather_frag(W, kt_ + 1, wn, 1, 0, lane);              \
                BN[3] = gather_frag(W, kt_ + 1, wn, 1, 1, lane);              \
            }                                                                 \
        }                                                                     \
        bf16x8 aF[4][2];                                                      \
        _Pragma("unroll") for (int m = 0; m < 4; ++m)                         \
        _Pragma("unroll") for (int ks = 0; ks < 2; ++ks)                      \
            aF[m][ks] = *(const bf16x8*)(Ar_ + (m * 16 + l15) * 128           \
                            + (((ks * 4 + l4) ^ sw) << 4));                   \
        _Pragma("unroll") for (int ks = 0; ks < 2; ++ks)                      \
        _Pragma("unroll") for (int m = 0; m < 4; ++m)                         \
        _Pragma("unroll") for (int n = 0; n < 2; ++n)                         \
            acc[m][n] = __builtin_amdgcn_mfma_f32_16x16x32_bf16(              \
                aF[m][ks], BC[ks * 2 + n], acc[m][n], 0, 0, 0);               \
        if (more_) *(bf16x8*)(Aw_ + awoff) = phi_pack(xn_);                   \
        __syncthreads();                                                      \
    }

template <bool DIRECT_B>
__global__ __launch_bounds__(THREADS, 2)
void kan_gemm(const float* __restrict__ X, const __bf16* __restrict__ Bimg,
              const float* __restrict__ W, float* __restrict__ Y) {
    __shared__ alignas(16) char lds[16384];   // A dbuf: 2 x 8KB

    const int tid  = threadIdx.x;
    const int lane = tid & 63;
    const int wn   = tid >> 6;       // 0..7 col group (32 cols)
    const int l15  = lane & 15;
    const int l4   = lane >> 4;
    const int brow0 = blockIdx.x * 64;

    // phi staging: one phi per thread per kt
    const int prow  = tid >> 3;          // 0..63
    const int pioff = tid & 7;           // 0..7
    const float* xsrc = X + (size_t)(brow0 + prow) * IF + pioff;   // +8 per kt
    const int awoff = prow * 128 + ((pioff ^ (prow & 7)) << 4);

    // A-frag read swizzle: row&7 == l15&7 for all m
    const int sw = l15 & 7;

    // B image base for this wave's column group
    const char* ib = (const char*)Bimg + (size_t)(wn * 2) * 1024 + lane * 16;
    // + kt*32768 + ks*16384 + n*1024

    f32x4 acc[4][2] = {};
    bf16x8 bA[4], bB[4];   // [ks*2+n]

    // ---- prologue: phi(kt=0) -> LDS[0]; B(kt=0) -> bA ----
    {
        float xc = xsrc[0];
        if (!DIRECT_B) {
            bA[0] = *(const bf16x8*)(ib);
            bA[1] = *(const bf16x8*)(ib + 1024);
            bA[2] = *(const bf16x8*)(ib + 16384);
            bA[3] = *(const bf16x8*)(ib + 17408);
        } else {
            bA[0] = gather_frag(W, 0, wn, 0, 0, lane);
            bA[1] = gather_frag(W, 0, wn, 0, 1, lane);
            bA[2] = gather_frag(W, 0, wn, 1, 0, lane);
            bA[3] = gather_frag(W, 0, wn, 1, 1, lane);
        }
        *(bf16x8*)(lds + awoff) = phi_pack(xc);
    }
    __syncthreads();

    for (int kt = 0; kt < NKT; kt += 2) {
        KT_BODY(kt, bA, bB)
        KT_BODY(kt + 1, bB, bA)
    }

    // ---- epilogue: C/D layout col=lane&15, row=(lane>>4)*4+r ----
#pragma unroll
    for (int m = 0; m < 4; ++m)
#pragma unroll
        for (int n = 0; n < 2; ++n) {
            int col  = wn * 32 + n * 16 + l15;
            int row0 = brow0 + m * 16 + l4 * 4;
#pragma unroll
            for (int r = 0; r < 4; ++r)
                Y[(size_t)(row0 + r) * OF + col] = acc[m][n][r];
        }
}

extern "C" void kernel_launch(void* const* d_in, const int* in_sizes, int n_in,
                              void* d_out, int out_size, void* d_ws, size_t ws_size,
                              hipStream_t stream) {
    const float* X = (const float*)d_in[0];
    const float* W = (const float*)d_in[1];
    float* Y = (float*)d_out;

    size_t need = (size_t)65536 * 16;                   // 1.0 MB image
    dim3 grid(M_TOTAL / 64);                            // 256 blocks

    if (d_ws != nullptr && ws_size >= need) {
        __bf16* img = (__bf16*)d_ws;
        repack_w<<<dim3(256), dim3(256), 0, stream>>>(W, img);
        kan_gemm<false><<<grid, dim3(THREADS), 0, stream>>>(X, img, W, Y);
    } else {
        kan_gemm<true><<<grid, dim3(THREADS), 0, stream>>>(X, nullptr, W, Y);
    }
}